// Round 10
// baseline (81.132 us; speedup 1.0000x reference)
//
#include <hip/hip_runtime.h>
#include <hip/hip_bf16.h>
#include <math.h>

using short8 = __attribute__((ext_vector_type(8))) short;
using f32x4 = __attribute__((ext_vector_type(4))) float;

#define MFMA16(a, b, c) __builtin_amdgcn_mfma_f32_16x16x32_bf16((a), (b), (c), 0, 0, 0)

namespace {
constexpr int NG_ = 256;
constexpr int H_ = 128;
constexpr int NTOT_ = 2048;
constexpr float SCALE_E = 0.08838834764831845f / 256.0f;  // (1/sqrt(H))/Ng
}  // namespace

__device__ __forceinline__ short f2bf(float x) {
  __hip_bfloat16 h = __float2bfloat16(x);
  return *reinterpret_cast<short*>(&h);
}
__device__ __forceinline__ float bf2f(short x) {
  return __uint_as_float(((unsigned)(unsigned short)x) << 16);
}
__device__ __forceinline__ float sigmoidf_(float x) { return 1.0f / (1.0f + expf(-x)); }
__device__ __forceinline__ float siluf_(float x) { return x / (1.0f + expf(-x)); }

__device__ __forceinline__ short8 neg8(short8 x) {
  short8 r;
#pragma unroll
  for (int i = 0; i < 8; ++i) r[i] = (short)(x[i] ^ (short)0x8000);
  return r;
}
// fragment read from a [rows][128] bf16 LDS tile, XOR-swizzled
__device__ __forceinline__ short8 ldf(const short* buf, int row, int kk) {
  return *(const short8*)&buf[(row * 128 + kk) ^ ((row & 7) << 3)];
}
// fragment read from a [rows][64] bf16 LDS tile, XOR-swizzled
__device__ __forceinline__ short8 ldf64(const short* buf, int row, int kk) {
  return *(const short8*)&buf[(row * 64 + kk) ^ ((row & 7) << 3)];
}
__device__ __forceinline__ short8 cvt8(const float* src) {
  float4 lo = *(const float4*)src, hi = *(const float4*)(src + 4);
  short8 v;
  v[0] = f2bf(lo.x); v[1] = f2bf(lo.y); v[2] = f2bf(lo.z); v[3] = f2bf(lo.w);
  v[4] = f2bf(hi.x); v[5] = f2bf(hi.y); v[6] = f2bf(hi.z); v[7] = f2bf(hi.w);
  return v;
}
// fractional coords for one node: solve cell^T f = p, frac
__device__ __forceinline__ void frac3(const float* cg, const float* p3,
                                      float* dst) {
  float A00 = cg[0], A01 = cg[3], A02 = cg[6];
  float A10 = cg[1], A11 = cg[4], A12 = cg[7];
  float A20 = cg[2], A21 = cg[5], A22 = cg[8];
  float b00 = A11 * A22 - A12 * A21;
  float b01 = A02 * A21 - A01 * A22;
  float b02 = A01 * A12 - A02 * A11;
  float b10 = A12 * A20 - A10 * A22;
  float b11 = A00 * A22 - A02 * A20;
  float b12 = A02 * A10 - A00 * A12;
  float b20 = A10 * A21 - A11 * A20;
  float b21 = A01 * A20 - A00 * A21;
  float b22 = A00 * A11 - A01 * A10;
  float det = A00 * b00 + A01 * b10 + A02 * b20;
  float inv = 1.0f / det;
  float p0 = p3[0], p1 = p3[1], p2 = p3[2];
  float f0 = (b00 * p0 + b01 * p1 + b02 * p2) * inv;
  float f1 = (b10 * p0 + b11 * p1 + b12 * p2) * inv;
  float f2 = (b20 * p0 + b21 * p1 + b22 * p2) * inv;
  dst[0] = f0 - floorf(f0);
  dst[1] = f1 - floorf(f1);
  dst[2] = f2 - floorf(f2);
}

// =====================================================================
// K_mono: ONE launch, 64 blocks = (g, 32-row tile). No cross-block deps.
// Each block: Q rows + gates + row-trig once, then serial 4-chunk loop
// {stage nf cols, K/V/VG GEMM (B direct from L2), col-trig, E, PV-accum}.
// =====================================================================
__global__ __launch_bounds__(512) void k_mono(
    const float* __restrict__ nf, const float* __restrict__ Wqkv,
    const float* __restrict__ Wvg, const float* __restrict__ bvg,
    const float* __restrict__ Whg, const float* __restrict__ bhg,
    const float* __restrict__ Wmg, const float* __restrict__ bmg,
    const float* __restrict__ cell, const float* __restrict__ pos,
    const int* __restrict__ nvec, const float* __restrict__ w,
    float* __restrict__ out, float* __restrict__ out_gate) {
  __shared__ short sNR[32 * 128];  // nf rows
  __shared__ short sQA[32 * 128];  // silu(q) rows, deinterleaved
  __shared__ short sCr[32 * 128];  // sqrt(w)*cos rows
  __shared__ short sSr[32 * 128];
  __shared__ short sNC[64 * 128];  // nf cols (per chunk)
  __shared__ short sKA[64 * 128];  // silu(k) cols, deinterleaved
  __shared__ short sCc[64 * 128];
  __shared__ short sSc[64 * 128];
  __shared__ short sVT[128 * 64];  // gated V, d-major
  __shared__ short sE[32 * 64];
  __shared__ float fr_sh[32 * 4];
  __shared__ float fc_sh[64 * 4];
  __shared__ int nv_sh[128 * 3];
  __shared__ float w_sh[128];
  __shared__ float GF_sh[32];

  const int tid = threadIdx.x;
  const int bid = blockIdx.x;
  const int g = bid >> 3, rt = bid & 7;
  const int R0 = rt * 32;
  const int gn = g * NG_;
  const int wid = tid >> 6, lane = tid & 63;
  const int frow = lane & 15, kq = (lane >> 4) * 8;
  const int orow = (lane >> 4) * 4, ocol = lane & 15;
  const int rfrag = wid >> 2;  // E/PV row frag (0..1)
  const int cfrag = wid & 3;   // E col frag / PV d-block (0..3)

  // ---------------- phase 0: stage rows + trig inputs
  {
    int row = tid >> 4, c8 = (tid & 15) * 8;
    *(short8*)&sNR[(row * 128 + c8) ^ ((row & 7) << 3)] =
        cvt8(nf + (size_t)(gn + R0 + row) * H_ + c8);
  }
  if (tid < 128) {
    nv_sh[tid * 3 + 0] = nvec[((size_t)g * 128 + tid) * 3 + 0];
    nv_sh[tid * 3 + 1] = nvec[((size_t)g * 128 + tid) * 3 + 1];
    nv_sh[tid * 3 + 2] = nvec[((size_t)g * 128 + tid) * 3 + 2];
    w_sh[tid] = sqrtf(w[(size_t)g * 128 + tid]);
  }
  if (tid < 32)
    frac3(cell + (size_t)g * 9, pos + (size_t)(gn + R0 + tid) * 3,
          &fr_sh[tid * 4]);
  __syncthreads();  // bar A

  // ---------------- phase 1: Q GEMM (B direct from L2), row trig, gates
  {
    const int qr = wid >> 2;        // 0..1 row frag
    const int cb = (wid & 3) * 32;  // storage col base
    const float* brow[2];
#pragma unroll
    for (int j = 0; j < 2; ++j) {
      int s = cb + j * 16 + frow;
      int wr = (s < 64) ? (2 * s) : (2 * (s - 64) + 1);
      brow[j] = Wqkv + (size_t)wr * H_;
    }
    f32x4 qa[2] = {};
#pragma unroll
    for (int ks = 0; ks < 4; ++ks) {
      int kk = ks * 32 + kq;
      short8 a = ldf(sNR, qr * 16 + frow, kk);
#pragma unroll
      for (int j = 0; j < 2; ++j) qa[j] = MFMA16(a, cvt8(brow[j] + kk), qa[j]);
    }
#pragma unroll
    for (int j = 0; j < 2; ++j) {
      int scol = cb + j * 16 + ocol;
#pragma unroll
      for (int r = 0; r < 4; ++r) {
        int row = qr * 16 + orow + r;
        sQA[(row * 128 + scol) ^ ((row & 7) << 3)] = f2bf(siluf_(qa[j][r]));
      }
    }
  }
  {  // row trig: 16 threads/node x 8 m
    int ln = tid >> 4, m0 = (tid & 15) * 8;
    float f0 = fr_sh[ln * 4 + 0], f1 = fr_sh[ln * 4 + 1], f2 = fr_sh[ln * 4 + 2];
    short8 pc, ps;
#pragma unroll
    for (int i = 0; i < 8; ++i) {
      int m = m0 + i;
      float dot = f0 * (float)nv_sh[m * 3] + f1 * (float)nv_sh[m * 3 + 1] +
                  f2 * (float)nv_sh[m * 3 + 2];
      float tr = dot - floorf(dot);
      float sq = w_sh[m];
      pc[i] = f2bf(sq * __builtin_amdgcn_cosf(tr));
      ps[i] = f2bf(sq * __builtin_amdgcn_sinf(tr));
    }
    *(short8*)&sCr[(ln * 128 + m0) ^ ((ln & 7) << 3)] = pc;
    *(short8*)&sSr[(ln * 128 + m0) ^ ((ln & 7) << 3)] = ps;
  }
  if (tid < 32) {  // per-node gates from sNR
    float hg = 0.f, mg = 0.f;
#pragma unroll 8
    for (int c = 0; c < 128; ++c) {
      float s = bf2f(sNR[(tid * 128 + c) ^ ((tid & 7) << 3)]);
      hg += s * Whg[c];
      mg += s * Wmg[c];
    }
    GF_sh[tid] = 1.0f + 0.2f * tanhf(hg + bhg[0]);
    out_gate[gn + R0 + tid] = sigmoidf_(mg + bmg[0]);
  }

  f32x4 oacc[2] = {};  // PV accumulator, persists across chunks

  for (int c4 = 0; c4 < 4; ++c4) {
    const int C0 = c4 * 64;
    __syncthreads();  // bar B: previous chunk's readers done (or phase 1)
    // ---- stage nf cols + col frac coords
#pragma unroll
    for (int it = 0; it < 2; ++it) {
      int e = tid + it * 512;
      int row = e >> 4, c8 = (e & 15) * 8;
      *(short8*)&sNC[(row * 128 + c8) ^ ((row & 7) << 3)] =
          cvt8(nf + (size_t)(gn + C0 + row) * H_ + c8);
    }
    if (tid < 64)
      frac3(cell + (size_t)g * 9, pos + (size_t)(gn + C0 + tid) * 3,
            &fc_sh[tid * 4]);
    __syncthreads();  // bar C: sNC, fc_sh ready
    // ---- col trig: 8 threads/node x 16 m
    {
      int cn = tid >> 3, mb = (tid & 7) * 16;
      float f0 = fc_sh[cn * 4 + 0], f1 = fc_sh[cn * 4 + 1],
            f2 = fc_sh[cn * 4 + 2];
#pragma unroll
      for (int h2 = 0; h2 < 2; ++h2) {
        int m0 = mb + h2 * 8;
        short8 pc, ps;
#pragma unroll
        for (int i = 0; i < 8; ++i) {
          int m = m0 + i;
          float dot = f0 * (float)nv_sh[m * 3] + f1 * (float)nv_sh[m * 3 + 1] +
                      f2 * (float)nv_sh[m * 3 + 2];
          float tr = dot - floorf(dot);
          float sq = w_sh[m];
          pc[i] = f2bf(sq * __builtin_amdgcn_cosf(tr));
          ps[i] = f2bf(sq * __builtin_amdgcn_sinf(tr));
        }
        *(short8*)&sCc[(cn * 128 + m0) ^ ((cn & 7) << 3)] = pc;
        *(short8*)&sSc[(cn * 128 + m0) ^ ((cn & 7) << 3)] = ps;
      }
    }
    // ---- K GEMM (64 col-nodes x 128 storage cols, deinterleave perm)
    {
      const int ra = wid & 3;         // col-node frag
      const int cg_ = (wid >> 2) * 64;  // storage col group
      const float* brow[4];
#pragma unroll
      for (int j = 0; j < 4; ++j) {
        int s = cg_ + j * 16 + frow;
        int wr = 128 + ((s < 64) ? (2 * s) : (2 * (s - 64) + 1));
        brow[j] = Wqkv + (size_t)wr * H_;
      }
      f32x4 kacc[4] = {};
#pragma unroll
      for (int ks = 0; ks < 4; ++ks) {
        int kk = ks * 32 + kq;
        short8 a = ldf(sNC, ra * 16 + frow, kk);
#pragma unroll
        for (int j = 0; j < 4; ++j)
          kacc[j] = MFMA16(a, cvt8(brow[j] + kk), kacc[j]);
      }
#pragma unroll
      for (int j = 0; j < 4; ++j) {
        int scol = cg_ + j * 16 + ocol;
#pragma unroll
        for (int r = 0; r < 4; ++r) {
          int row = ra * 16 + orow + r;
          sKA[(row * 128 + scol) ^ ((row & 7) << 3)] = f2bf(siluf_(kacc[j][r]));
        }
      }
      // ---- V + VG GEMM (same frag assignment; lanes align v/vg)
      const float* vrow[4];
      const float* grow[4];
#pragma unroll
      for (int j = 0; j < 4; ++j) {
        int d = cg_ + j * 16 + frow;
        vrow[j] = Wqkv + (size_t)(256 + d) * H_;
        grow[j] = Wvg + (size_t)d * H_;
      }
      f32x4 vacc[4] = {}, ga[4] = {};
#pragma unroll
      for (int ks = 0; ks < 4; ++ks) {
        int kk = ks * 32 + kq;
        short8 a = ldf(sNC, ra * 16 + frow, kk);
#pragma unroll
        for (int j = 0; j < 4; ++j) {
          vacc[j] = MFMA16(a, cvt8(vrow[j] + kk), vacc[j]);
          ga[j] = MFMA16(a, cvt8(grow[j] + kk), ga[j]);
        }
      }
#pragma unroll
      for (int j = 0; j < 4; ++j) {
        int d = cg_ + j * 16 + ocol;
        float bv = bvg[d];
#pragma unroll
        for (int r = 0; r < 4; ++r) {
          int nl = ra * 16 + orow + r;
          float val = vacc[j][r] * sigmoidf_(ga[j][r] + bv);
          sVT[(d * 64 + nl) ^ ((d & 7) << 3)] = f2bf(val);
        }
      }
    }
    __syncthreads();  // bar D: sKA/sCc/sSc/sVT ready
    // ---- E fragment (16x16 per wave)
    {
      f32x4 gc = {}, gs = {}, qc = {}, qs = {};
#pragma unroll
      for (int ks = 0; ks < 4; ++ks) {
        int kk = ks * 32 + kq, kk2 = (kk + 64) & 127;
        short8 aq = ldf(sQA, rfrag * 16 + frow, kk);
        short8 ka = ldf(sKA, cfrag * 16 + frow, kk);
        short8 t = ldf(sKA, cfrag * 16 + frow, kk2);
        short8 kb = (ks >= 2) ? neg8(t) : t;
        gc = MFMA16(aq, ka, gc);
        gs = MFMA16(aq, kb, gs);
      }
#pragma unroll
      for (int ks = 0; ks < 8; ++ks) {
        const bool lo = ks < 4;
        int kk = (ks & 3) * 32 + kq;
        short8 cr = ldf(sCr, rfrag * 16 + frow, kk);
        short8 sr = ldf(sSr, rfrag * 16 + frow, kk);
        short8 xr = lo ? cr : sr;
        short8 yr = lo ? sr : neg8(cr);
        short8 xc = ldf(lo ? sCc : sSc, cfrag * 16 + frow, kk);
        qc = MFMA16(xr, xc, qc);
        qs = MFMA16(yr, xc, qs);
      }
      int col = cfrag * 16 + ocol;
#pragma unroll
      for (int r = 0; r < 4; ++r) {
        int row = rfrag * 16 + orow + r;
        float ev = gc[r] * qc[r] + gs[r] * qs[r];
        sE[(row * 64 + col) ^ ((row & 7) << 3)] = f2bf(ev);
      }
    }
    __syncthreads();  // bar E: sE ready
    // ---- PV: accumulate into oacc (register, fixed chunk order)
#pragma unroll
    for (int ks = 0; ks < 2; ++ks) {
      int kk = ks * 32 + kq;
      short8 a = ldf64(sE, rfrag * 16 + frow, kk);
#pragma unroll
      for (int j = 0; j < 2; ++j) {
        short8 b = ldf64(sVT, cfrag * 32 + j * 16 + frow, kk);
        oacc[j] = MFMA16(a, b, oacc[j]);
      }
    }
  }
  // ---------------- epilogue: gated output, written exactly once
#pragma unroll
  for (int r = 0; r < 4; ++r) {
    int lrow = rfrag * 16 + orow + r;
    float fct = GF_sh[lrow] * SCALE_E;
#pragma unroll
    for (int j = 0; j < 2; ++j)
      out[(size_t)(gn + R0 + lrow) * H_ + cfrag * 32 + j * 16 + ocol] =
          oacc[j][r] * fct;
  }
}

extern "C" void kernel_launch(void* const* d_in, const int* in_sizes, int n_in,
                              void* d_out, int out_size, void* d_ws,
                              size_t ws_size, hipStream_t stream) {
  const float* node_feat = (const float*)d_in[0];
  const float* positions = (const float*)d_in[1];
  const float* cell = (const float*)d_in[2];
  const float* w = (const float*)d_in[3];
  const float* Wqkv = (const float*)d_in[4];
  const float* Wvg = (const float*)d_in[5];
  const float* bvg = (const float*)d_in[6];
  const float* Whg = (const float*)d_in[7];
  const float* bhg = (const float*)d_in[8];
  const float* Wmg = (const float*)d_in[9];
  const float* bmg = (const float*)d_in[10];
  const int* nvec = (const int*)d_in[11];
  float* out = (float*)d_out;
  float* out_gate = out + (size_t)NTOT_ * H_;

  k_mono<<<64, 512, 0, stream>>>(node_feat, Wqkv, Wvg, bvg, Whg, bhg, Wmg, bmg,
                                 cell, positions, nvec, w, out, out_gate);
}

// Round 11
// 24.527 us; speedup vs baseline: 3.3078x; 3.3078x over previous
//
#include <hip/hip_runtime.h>
#include <hip/hip_bf16.h>
#include <math.h>

using short8 = __attribute__((ext_vector_type(8))) short;
using f32x4 = __attribute__((ext_vector_type(4))) float;

#define MFMA16(a, b, c) __builtin_amdgcn_mfma_f32_16x16x32_bf16((a), (b), (c), 0, 0, 0)

namespace {
constexpr int NG_ = 256;
constexpr int H_ = 128;
constexpr int NTOT_ = 2048;
constexpr float SCALE_E = 0.08838834764831845f / 256.0f;  // (1/sqrt(H))/Ng

// workspace offsets in BYTES
constexpr size_t OFF_QA = 0;               // bf16 [2048][128] = [aq|bq]
constexpr size_t OFF_KA = 524288;          // bf16 [2048][128] = [ak|bk]
constexpr size_t OFF_VT = 1048576;         // bf16 [8][128][256] (d-major)
constexpr size_t OFF_CT = 1572864;         // bf16 [2048][128] sqrt(w)*cos
constexpr size_t OFF_ST = 2097152;         // bf16 [2048][128] sqrt(w)*sin
constexpr size_t OFF_GF = 2621440;         // f32 [2048]
}  // namespace

__device__ __forceinline__ short f2bf(float x) {
  __hip_bfloat16 h = __float2bfloat16(x);
  return *reinterpret_cast<short*>(&h);
}
__device__ __forceinline__ float bf2f(short x) {
  return __uint_as_float(((unsigned)(unsigned short)x) << 16);
}
__device__ __forceinline__ float sigmoidf_(float x) { return 1.0f / (1.0f + expf(-x)); }
__device__ __forceinline__ float siluf_(float x) { return x / (1.0f + expf(-x)); }

__device__ __forceinline__ short8 neg8(short8 x) {
  short8 r;
#pragma unroll
  for (int i = 0; i < 8; ++i) r[i] = (short)(x[i] ^ (short)0x8000);
  return r;
}
__device__ __forceinline__ short8 ldf(const short* buf, int row, int kk) {
  return *(const short8*)&buf[(row * 128 + kk) ^ ((row & 7) << 3)];
}
__device__ __forceinline__ short8 ldf64(const short* buf, int row, int kk) {
  return *(const short8*)&buf[(row * 64 + kk) ^ ((row & 7) << 3)];
}
__device__ __forceinline__ short8 cvt8(const float* src) {
  float4 lo = *(const float4*)src, hi = *(const float4*)(src + 4);
  short8 v;
  v[0] = f2bf(lo.x); v[1] = f2bf(lo.y); v[2] = f2bf(lo.z); v[3] = f2bf(lo.w);
  v[4] = f2bf(hi.x); v[5] = f2bf(hi.y); v[6] = f2bf(hi.z); v[7] = f2bf(hi.w);
  return v;
}

// ================= K_prep: GEMM+activations (bid<128, 32x256 tiles, B direct
// from global with deinterleave-by-permutation) + trig/zero blocks (128..191)
__global__ __launch_bounds__(512) void k_prep(
    const float* __restrict__ nf, const float* __restrict__ Wqkv,
    const float* __restrict__ Wvg, const float* __restrict__ bvg,
    const float* __restrict__ Whg, const float* __restrict__ bhg,
    const float* __restrict__ Wmg, const float* __restrict__ bmg,
    const float* __restrict__ cell, const float* __restrict__ pos,
    const int* __restrict__ nvec, const float* __restrict__ w,
    short* __restrict__ QA, short* __restrict__ KA, short* __restrict__ VT,
    short* __restrict__ CT, short* __restrict__ ST, float* __restrict__ GF,
    float* __restrict__ out_gate, float* __restrict__ out_zero) {
  __shared__ short sA[32 * 128];       // nf rows, bf16 swizzled (8 KB)
  __shared__ short gate_sh[32 * 128];  // sigmoid(vg) (8 KB, h==1 only)
  __shared__ short vt_sh[128 * 32];    // gated V d-major (8 KB, h==1 only)
  const int tid = threadIdx.x;
  const int bid = blockIdx.x;
  if (bid < 128) {
    const int r_tile = bid >> 1, h = bid & 1;
    const int n0 = r_tile * 32;
    {
      int row = tid >> 4, c8 = (tid & 15) * 8;
      *(short8*)&sA[(row * 128 + c8) ^ ((row & 7) << 3)] =
          cvt8(nf + (size_t)(n0 + row) * H_ + c8);
    }
    __syncthreads();
    const int wid = tid >> 6, lane = tid & 63;
    const int frow = lane & 15, kq = (lane >> 4) * 8;
    const int orow = (lane >> 4) * 4, ocol = lane & 15;
    const float* brow[2];
#pragma unroll
    for (int j = 0; j < 2; ++j) {
      int c = wid * 32 + j * 16 + frow;  // storage col 0..255
      if (h == 0) {
        int wr;
        if (c < 128)
          wr = (c < 64) ? (2 * c) : (2 * (c - 64) + 1);
        else {
          int q = c - 128;
          wr = 128 + ((q < 64) ? (2 * q) : (2 * (q - 64) + 1));
        }
        brow[j] = Wqkv + (size_t)wr * H_;
      } else {
        int wr = 256 + c;
        brow[j] = (wr < 384) ? (Wqkv + (size_t)wr * H_)
                             : (Wvg + (size_t)(wr - 384) * H_);
      }
    }
    f32x4 acc[2][2] = {};
#pragma unroll
    for (int ks = 0; ks < 4; ++ks) {
      int kk = ks * 32 + kq;
      short8 a[2], b[2];
#pragma unroll
      for (int i = 0; i < 2; ++i) a[i] = ldf(sA, i * 16 + frow, kk);
#pragma unroll
      for (int j = 0; j < 2; ++j) b[j] = cvt8(brow[j] + kk);
#pragma unroll
      for (int i = 0; i < 2; ++i)
#pragma unroll
        for (int j = 0; j < 2; ++j) acc[i][j] = MFMA16(a[i], b[j], acc[i][j]);
    }
    if (h == 0) {
#pragma unroll
      for (int i = 0; i < 2; ++i)
#pragma unroll
        for (int j = 0; j < 2; ++j) {
          int c = wid * 32 + j * 16 + ocol;  // storage col (perm deinterleaved)
#pragma unroll
          for (int r = 0; r < 4; ++r) {
            int node = n0 + i * 16 + orow + r;
            if (c < 128)
              QA[(size_t)node * 128 + c] = f2bf(siluf_(acc[i][j][r]));
            else
              KA[(size_t)node * 128 + (c - 128)] = f2bf(siluf_(acc[i][j][r]));
          }
        }
    } else {
      if (wid >= 4) {
#pragma unroll
        for (int i = 0; i < 2; ++i)
#pragma unroll
          for (int j = 0; j < 2; ++j) {
            int d = (wid - 4) * 32 + j * 16 + ocol;
#pragma unroll
            for (int r = 0; r < 4; ++r) {
              int nl = i * 16 + orow + r;
              gate_sh[nl * 128 + d] = f2bf(sigmoidf_(acc[i][j][r] + bvg[d]));
            }
          }
      }
      __syncthreads();
      if (wid < 4) {
#pragma unroll
        for (int i = 0; i < 2; ++i)
#pragma unroll
          for (int j = 0; j < 2; ++j) {
            int d = wid * 32 + j * 16 + ocol;
#pragma unroll
            for (int r = 0; r < 4; ++r) {
              int nl = i * 16 + orow + r;
              float gate = bf2f(gate_sh[nl * 128 + d]);
              vt_sh[(d * 32 + nl) ^ ((d & 3) << 3)] =
                  f2bf(acc[i][j][r] * gate);
            }
          }
      }
      if (tid < 32) {
        int nl = tid;
        float hg = 0.f, mg = 0.f;
#pragma unroll 8
        for (int c = 0; c < 128; ++c) {
          float s = bf2f(sA[(nl * 128 + c) ^ ((nl & 7) << 3)]);
          hg += s * Whg[c];
          mg += s * Wmg[c];
        }
        int node = n0 + nl;
        GF[node] = 1.0f + 0.2f * tanhf(hg + bhg[0]);
        out_gate[node] = sigmoidf_(mg + bmg[0]);
      }
      __syncthreads();
      const int g_idx = n0 >> 8, nbase = n0 & 255;
      {
        int d = tid >> 2, n8 = (tid & 3) * 8;
        short8 v = *(const short8*)&vt_sh[(d * 32 + n8) ^ ((d & 3) << 3)];
        *(short8*)&VT[((size_t)(g_idx * 128 + d)) * 256 + nbase + n8] = v;
      }
    }
  } else {
    const int b = bid - 128;
    const int g = b >> 3, n0 = (b & 7) * 32;
    {
      float4 z = {0.f, 0.f, 0.f, 0.f};
      float* oz = out_zero + (size_t)b * 4096 + tid * 8;
      *(float4*)oz = z;
      *(float4*)(oz + 4) = z;
    }
    __shared__ float f_sh[32 * 4];
    __shared__ int nv_sh[128 * 3];
    __shared__ float w_sh[128];
    if (tid < 32) {
      const float* cg = cell + (size_t)g * 9;
      float A00 = cg[0], A01 = cg[3], A02 = cg[6];
      float A10 = cg[1], A11 = cg[4], A12 = cg[7];
      float A20 = cg[2], A21 = cg[5], A22 = cg[8];
      float b00 = A11 * A22 - A12 * A21;
      float b01 = A02 * A21 - A01 * A22;
      float b02 = A01 * A12 - A02 * A11;
      float b10 = A12 * A20 - A10 * A22;
      float b11 = A00 * A22 - A02 * A20;
      float b12 = A02 * A10 - A00 * A12;
      float b20 = A10 * A21 - A11 * A20;
      float b21 = A01 * A20 - A00 * A21;
      float b22 = A00 * A11 - A01 * A10;
      float det = A00 * b00 + A01 * b10 + A02 * b20;
      float inv = 1.0f / det;
      const int node = g * NG_ + n0 + tid;
      float p0 = pos[(size_t)node * 3 + 0];
      float p1 = pos[(size_t)node * 3 + 1];
      float p2 = pos[(size_t)node * 3 + 2];
      float f0 = (b00 * p0 + b01 * p1 + b02 * p2) * inv;
      float f1 = (b10 * p0 + b11 * p1 + b12 * p2) * inv;
      float f2 = (b20 * p0 + b21 * p1 + b22 * p2) * inv;
      f_sh[tid * 4 + 0] = f0 - floorf(f0);
      f_sh[tid * 4 + 1] = f1 - floorf(f1);
      f_sh[tid * 4 + 2] = f2 - floorf(f2);
    }
    if (tid < 128) {
      nv_sh[tid * 3 + 0] = nvec[((size_t)g * 128 + tid) * 3 + 0];
      nv_sh[tid * 3 + 1] = nvec[((size_t)g * 128 + tid) * 3 + 1];
      nv_sh[tid * 3 + 2] = nvec[((size_t)g * 128 + tid) * 3 + 2];
      w_sh[tid] = sqrtf(w[(size_t)g * 128 + tid]);
    }
    __syncthreads();
    const int n_l = tid >> 4, m0 = (tid & 15) * 8;
    float f0 = f_sh[n_l * 4 + 0], f1 = f_sh[n_l * 4 + 1], f2 = f_sh[n_l * 4 + 2];
    short8 pc, ps;
#pragma unroll
    for (int i = 0; i < 8; ++i) {
      int m = m0 + i;
      float dot = f0 * (float)nv_sh[m * 3] + f1 * (float)nv_sh[m * 3 + 1] +
                  f2 * (float)nv_sh[m * 3 + 2];
      float tr = dot - floorf(dot);
      float sq = w_sh[m];
      pc[i] = f2bf(sq * __builtin_amdgcn_cosf(tr));
      ps[i] = f2bf(sq * __builtin_amdgcn_sinf(tr));
    }
    const int node = g * NG_ + n0 + n_l;
    *(short8*)&CT[(size_t)node * 128 + m0] = pc;
    *(short8*)&ST[(size_t)node * 128 + m0] = ps;
  }
}

// ================= K_EV2: single-shot partial E*V over one 64-col chunk,
// gated + atomically accumulated into out (zeroed by k_prep).
// XCD-sibling swizzle: the 4 col-chunk blocks of one (g,rt) share bid%8,
// so round-robin dispatch puts them on the same XCD (L2-local row-side
// reads + same-L2 atomics).
__global__ __launch_bounds__(512) void k_EV2(
    const short* __restrict__ QA, const short* __restrict__ KA,
    const short* __restrict__ VT, const short* __restrict__ CT,
    const short* __restrict__ ST, const float* __restrict__ GF,
    float* __restrict__ out) {
  __shared__ short smem[47104];  // 92 KB
  __shared__ float GF_sh[32];
  short* tQ  = smem;             // 32x128
  short* tCr = smem + 4096;
  short* tSr = smem + 8192;
  short* tKA = smem + 12288;     // 64x128
  short* tCc = smem + 20480;
  short* tSc = smem + 28672;
  short* tV  = smem + 36864;     // 128(d) x 64(n')
  short* tE  = smem + 45056;     // 32x64
  const int tid = threadIdx.x;
  const int bid = blockIdx.x;
  // decode swizzled block id: bid = hi*32 + cc*8 + lo, q = hi*8 + lo
  const int cc = (bid >> 3) & 3;
  const int q = (bid & 7) | ((bid >> 5) << 3);  // 0..63
  const int g = q >> 3;
  const int rt = q & 7;
  const int R0 = rt * 32, C0 = cc * 64;
  const int gn = g * NG_;
  const int wid = tid >> 6, lane = tid & 63;
  const int frow = lane & 15, kq = (lane >> 4) * 8;
  const int orow = (lane >> 4) * 4, ocol = lane & 15;
  const int rfrag = wid >> 2;          // 0..1
  const int cfrag = wid & 3;           // 0..3 (E col frag / PV d block)

  // row-side staging: 512 threads cover 32x16 short8; GF prefetch
  {
    int row = tid >> 4, c8 = (tid & 15) * 8;
    int idx = (row * 128 + c8) ^ ((row & 7) << 3);
    size_t ga = (size_t)(gn + R0 + row) * 128 + c8;
    *(short8*)&tQ[idx] = *(const short8*)&QA[ga];
    *(short8*)&tCr[idx] = *(const short8*)&CT[ga];
    *(short8*)&tSr[idx] = *(const short8*)&ST[ga];
  }
  if (tid < 32) GF_sh[tid] = GF[gn + R0 + tid] * SCALE_E;
  // col-side staging: KA/Cc/Sc (64x128) + V (128x64)
#pragma unroll
  for (int it = 0; it < 2; ++it) {
    int e = tid + it * 512;
    int row = e >> 4, c8 = (e & 15) * 8;
    int idx = (row * 128 + c8) ^ ((row & 7) << 3);
    size_t ga = (size_t)(gn + C0 + row) * 128 + c8;
    *(short8*)&tKA[idx] = *(const short8*)&KA[ga];
    *(short8*)&tCc[idx] = *(const short8*)&CT[ga];
    *(short8*)&tSc[idx] = *(const short8*)&ST[ga];
    int d = e >> 3, n8 = (e & 7) * 8;
    *(short8*)&tV[(d * 64 + n8) ^ ((d & 7) << 3)] =
        *(const short8*)&VT[((size_t)g * 128 + d) * 256 + C0 + n8];
  }
  __syncthreads();
  // ---- E fragment: each wave one 16x16 frag at (rfrag, cfrag)
  f32x4 gc = {}, gs = {}, qc = {}, qs = {};
#pragma unroll
  for (int ks = 0; ks < 4; ++ks) {
    int kk = ks * 32 + kq, kk2 = (kk + 64) & 127;
    short8 aq = ldf(tQ, rfrag * 16 + frow, kk);
    short8 ka = ldf(tKA, cfrag * 16 + frow, kk);
    short8 t = ldf(tKA, cfrag * 16 + frow, kk2);
    short8 kb = (ks >= 2) ? neg8(t) : t;
    gc = MFMA16(aq, ka, gc);
    gs = MFMA16(aq, kb, gs);
  }
#pragma unroll
  for (int ks = 0; ks < 8; ++ks) {
    const bool lo = ks < 4;
    int kk = (ks & 3) * 32 + kq;
    short8 cr = ldf(tCr, rfrag * 16 + frow, kk);
    short8 sr = ldf(tSr, rfrag * 16 + frow, kk);
    short8 xr = lo ? cr : sr;
    short8 yr = lo ? sr : neg8(cr);
    short8 xc = ldf(lo ? tCc : tSc, cfrag * 16 + frow, kk);
    qc = MFMA16(xr, xc, qc);
    qs = MFMA16(yr, xc, qs);
  }
  {
    int col = cfrag * 16 + ocol;
#pragma unroll
    for (int r = 0; r < 4; ++r) {
      int row = rfrag * 16 + orow + r;
      float ev = gc[r] * qc[r] + gs[r] * qs[r];
      tE[(row * 64 + col) ^ ((row & 7) << 3)] = f2bf(ev);
    }
  }
  __syncthreads();
  // ---- PV partial: wave (rfrag, cfrag) -> rows rfrag*16, d cols cfrag*32..+31
  f32x4 oacc[2] = {};
#pragma unroll
  for (int ks = 0; ks < 2; ++ks) {
    int kk = ks * 32 + kq;
    short8 a = ldf64(tE, rfrag * 16 + frow, kk);
#pragma unroll
    for (int j = 0; j < 2; ++j) {
      short8 b = ldf64(tV, cfrag * 32 + j * 16 + frow, kk);
      oacc[j] = MFMA16(a, b, oacc[j]);
    }
  }
  // gated atomic accumulate (gate row-constant, distributes over the sum)
#pragma unroll
  for (int r = 0; r < 4; ++r) {
    int lrow = rfrag * 16 + orow + r;
    float fct = GF_sh[lrow];
#pragma unroll
    for (int j = 0; j < 2; ++j)
      unsafeAtomicAdd(
          &out[(size_t)(gn + R0 + lrow) * H_ + cfrag * 32 + j * 16 + ocol],
          oacc[j][r] * fct);
  }
}

extern "C" void kernel_launch(void* const* d_in, const int* in_sizes, int n_in,
                              void* d_out, int out_size, void* d_ws,
                              size_t ws_size, hipStream_t stream) {
  const float* node_feat = (const float*)d_in[0];
  const float* positions = (const float*)d_in[1];
  const float* cell = (const float*)d_in[2];
  const float* w = (const float*)d_in[3];
  const float* Wqkv = (const float*)d_in[4];
  const float* Wvg = (const float*)d_in[5];
  const float* bvg = (const float*)d_in[6];
  const float* Whg = (const float*)d_in[7];
  const float* bhg = (const float*)d_in[8];
  const float* Wmg = (const float*)d_in[9];
  const float* bmg = (const float*)d_in[10];
  const int* nvec = (const int*)d_in[11];
  float* out = (float*)d_out;
  char* ws = (char*)d_ws;

  short* QA = (short*)(ws + OFF_QA);
  short* KA = (short*)(ws + OFF_KA);
  short* VT = (short*)(ws + OFF_VT);
  short* CT = (short*)(ws + OFF_CT);
  short* ST = (short*)(ws + OFF_ST);
  float* GF = (float*)(ws + OFF_GF);
  float* out_gate = out + (size_t)NTOT_ * H_;

  k_prep<<<192, 512, 0, stream>>>(node_feat, Wqkv, Wvg, bvg, Whg, bhg, Wmg, bmg,
                                  cell, positions, nvec, w, QA, KA, VT, CT, ST,
                                  GF, out_gate, out);
  k_EV2<<<256, 512, 0, stream>>>(QA, KA, VT, CT, ST, GF, out);
}

// Round 12
// 23.505 us; speedup vs baseline: 3.4516x; 1.0435x over previous
//
#include <hip/hip_runtime.h>
#include <hip/hip_bf16.h>
#include <math.h>

using short8 = __attribute__((ext_vector_type(8))) short;
using f32x4 = __attribute__((ext_vector_type(4))) float;

#define MFMA16(a, b, c) __builtin_amdgcn_mfma_f32_16x16x32_bf16((a), (b), (c), 0, 0, 0)

namespace {
constexpr int NG_ = 256;
constexpr int H_ = 128;
constexpr int NTOT_ = 2048;
constexpr float SCALE_E = 0.08838834764831845f / 256.0f;  // (1/sqrt(H))/Ng

// workspace offsets in BYTES
constexpr size_t OFF_QA = 0;               // bf16 [2048][128] = [aq|bq]
constexpr size_t OFF_KA = 524288;          // bf16 [2048][128] = [ak|bk]
constexpr size_t OFF_VT = 1048576;         // bf16 [8][128][256] (d-major)
constexpr size_t OFF_CT = 1572864;         // bf16 [2048][128] sqrt(w)*cos
constexpr size_t OFF_ST = 2097152;         // bf16 [2048][128] sqrt(w)*sin
constexpr size_t OFF_GF = 2621440;         // f32 [2048]
}  // namespace

__device__ __forceinline__ short f2bf(float x) {
  __hip_bfloat16 h = __float2bfloat16(x);  // RNE, single cvt op
  return *reinterpret_cast<short*>(&h);
}
__device__ __forceinline__ float bf2f(short x) {
  return __uint_as_float(((unsigned)(unsigned short)x) << 16);
}
__device__ __forceinline__ float sigmoidf_(float x) { return 1.0f / (1.0f + expf(-x)); }
__device__ __forceinline__ float siluf_(float x) { return x / (1.0f + expf(-x)); }

__device__ __forceinline__ short8 neg8(short8 x) {
  short8 r;
#pragma unroll
  for (int i = 0; i < 8; ++i) r[i] = (short)(x[i] ^ (short)0x8000);
  return r;
}
// fragment read from a [rows][128] bf16 LDS tile, XOR-swizzled
__device__ __forceinline__ short8 ldf(const short* buf, int row, int kk) {
  return *(const short8*)&buf[(row * 128 + kk) ^ ((row & 7) << 3)];
}
// fragment read from a [rows][64] bf16 LDS tile, XOR-swizzled
__device__ __forceinline__ short8 ldf64(const short* buf, int row, int kk) {
  return *(const short8*)&buf[(row * 64 + kk) ^ ((row & 7) << 3)];
}
__device__ __forceinline__ short8 cvt8(const float* src) {
  float4 lo = *(const float4*)src, hi = *(const float4*)(src + 4);
  short8 v;
  v[0] = f2bf(lo.x); v[1] = f2bf(lo.y); v[2] = f2bf(lo.z); v[3] = f2bf(lo.w);
  v[4] = f2bf(hi.x); v[5] = f2bf(hi.y); v[6] = f2bf(hi.z); v[7] = f2bf(hi.w);
  return v;
}

// ================= K_prep: GEMM+activations (bid<128, 32x256 tiles, B direct
// from global with deinterleave-by-permutation) + trig/zero blocks (128..191)
__global__ __launch_bounds__(512) void k_prep(
    const float* __restrict__ nf, const float* __restrict__ Wqkv,
    const float* __restrict__ Wvg, const float* __restrict__ bvg,
    const float* __restrict__ Whg, const float* __restrict__ bhg,
    const float* __restrict__ Wmg, const float* __restrict__ bmg,
    const float* __restrict__ cell, const float* __restrict__ pos,
    const int* __restrict__ nvec, const float* __restrict__ w,
    short* __restrict__ QA, short* __restrict__ KA, short* __restrict__ VT,
    short* __restrict__ CT, short* __restrict__ ST, float* __restrict__ GF,
    float* __restrict__ out_gate, float* __restrict__ out_zero) {
  __shared__ short sA[32 * 128];       // nf rows, bf16 swizzled (8 KB)
  __shared__ short gate_sh[32 * 128];  // sigmoid(vg)+  (8 KB, h==1 only)
  __shared__ short vt_sh[128 * 32];    // gated V d-major (8 KB, h==1 only)
  const int tid = threadIdx.x;
  const int bid = blockIdx.x;
  if (bid < 128) {
    const int r_tile = bid >> 1, h = bid & 1;
    const int n0 = r_tile * 32;
    // stage A (32x128): 512 threads x short8
    {
      int row = tid >> 4, c8 = (tid & 15) * 8;
      *(short8*)&sA[(row * 128 + c8) ^ ((row & 7) << 3)] =
          cvt8(nf + (size_t)(n0 + row) * H_ + c8);
    }
    __syncthreads();
    const int wid = tid >> 6, lane = tid & 63;
    const int frow = lane & 15, kq = (lane >> 4) * 8;
    const int orow = (lane >> 4) * 4, ocol = lane & 15;
    // per-lane weight row (deinterleave folded into permutation)
    int wrow[2];
    const float* brow[2];
#pragma unroll
    for (int j = 0; j < 2; ++j) {
      int c = wid * 32 + j * 16 + frow;  // storage col 0..255
      if (h == 0) {
        int wr;
        if (c < 128)
          wr = (c < 64) ? (2 * c) : (2 * (c - 64) + 1);
        else {
          int q = c - 128;
          wr = 128 + ((q < 64) ? (2 * q) : (2 * (q - 64) + 1));
        }
        wrow[j] = wr;
        brow[j] = Wqkv + (size_t)wr * H_;
      } else {
        int wr = 256 + c;
        wrow[j] = wr;
        brow[j] = (wr < 384) ? (Wqkv + (size_t)wr * H_)
                             : (Wvg + (size_t)(wr - 384) * H_);
      }
    }
    f32x4 acc[2][2] = {};
#pragma unroll
    for (int ks = 0; ks < 4; ++ks) {
      int kk = ks * 32 + kq;
      short8 a[2], b[2];
#pragma unroll
      for (int i = 0; i < 2; ++i) a[i] = ldf(sA, i * 16 + frow, kk);
#pragma unroll
      for (int j = 0; j < 2; ++j) b[j] = cvt8(brow[j] + kk);
#pragma unroll
      for (int i = 0; i < 2; ++i)
#pragma unroll
        for (int j = 0; j < 2; ++j) acc[i][j] = MFMA16(a[i], b[j], acc[i][j]);
    }
    if (h == 0) {
      // silu + direct contiguous stores (perm already deinterleaved)
#pragma unroll
      for (int i = 0; i < 2; ++i)
#pragma unroll
        for (int j = 0; j < 2; ++j) {
          int c = wid * 32 + j * 16 + ocol;  // storage col
          short* dst = (c < 128) ? (QA + c) : (KA + c - 128);
#pragma unroll
          for (int r = 0; r < 4; ++r) {
            int node = n0 + i * 16 + orow + r;
            dst[(size_t)node * 128] = f2bf(siluf_(acc[i][j][r]));
            dst += 0;  // keep dst per-r explicit below
          }
          // note: recompute address per r to keep it simple/correct
#pragma unroll
          for (int r = 0; r < 4; ++r) {
            int node = n0 + i * 16 + orow + r;
            if (c < 128)
              QA[(size_t)node * 128 + c] = f2bf(siluf_(acc[i][j][r]));
            else
              KA[(size_t)node * 128 + (c - 128)] = f2bf(siluf_(acc[i][j][r]));
          }
        }
    } else {
      // vg waves (wid>=4) write gates; v waves (wid<4) then gate+transpose
      if (wid >= 4) {
#pragma unroll
        for (int i = 0; i < 2; ++i)
#pragma unroll
          for (int j = 0; j < 2; ++j) {
            int d = (wid - 4) * 32 + j * 16 + ocol;
#pragma unroll
            for (int r = 0; r < 4; ++r) {
              int nl = i * 16 + orow + r;
              gate_sh[nl * 128 + d] = f2bf(sigmoidf_(acc[i][j][r] + bvg[d]));
            }
          }
      }
      __syncthreads();
      if (wid < 4) {
#pragma unroll
        for (int i = 0; i < 2; ++i)
#pragma unroll
          for (int j = 0; j < 2; ++j) {
            int d = wid * 32 + j * 16 + ocol;
#pragma unroll
            for (int r = 0; r < 4; ++r) {
              int nl = i * 16 + orow + r;
              float gate = bf2f(gate_sh[nl * 128 + d]);
              vt_sh[(d * 32 + nl) ^ ((d & 3) << 3)] =
                  f2bf(acc[i][j][r] * gate);
            }
          }
      }
      // per-node gates from sA
      if (tid < 32) {
        int nl = tid;
        float hg = 0.f, mg = 0.f;
#pragma unroll 8
        for (int c = 0; c < 128; ++c) {
          float s = bf2f(sA[(nl * 128 + c) ^ ((nl & 7) << 3)]);
          hg += s * Whg[c];
          mg += s * Wmg[c];
        }
        int node = n0 + nl;
        GF[node] = 1.0f + 0.2f * tanhf(hg + bhg[0]);
        out_gate[node] = sigmoidf_(mg + bmg[0]);
      }
      __syncthreads();
      // coalesced VT store: [g][d][256] short8
      const int g_idx = n0 >> 8, nbase = n0 & 255;
      {
        int d = tid >> 2, n8 = (tid & 3) * 8;
        short8 v = *(const short8*)&vt_sh[(d * 32 + n8) ^ ((d & 3) << 3)];
        *(short8*)&VT[((size_t)(g_idx * 128 + d)) * 256 + nbase + n8] = v;
      }
    }
  } else {
    const int b = bid - 128;
    const int g = b >> 3, n0 = (b & 7) * 32;
    // zero the update-output chunk (4096 floats per block)
    {
      float4 z = {0.f, 0.f, 0.f, 0.f};
      float* oz = out_zero + (size_t)b * 4096 + tid * 8;
      *(float4*)oz = z;
      *(float4*)(oz + 4) = z;
    }
    __shared__ float f_sh[32 * 4];
    __shared__ int nv_sh[128 * 3];
    __shared__ float w_sh[128];
    if (tid < 32) {
      const float* cg = cell + (size_t)g * 9;
      float A00 = cg[0], A01 = cg[3], A02 = cg[6];
      float A10 = cg[1], A11 = cg[4], A12 = cg[7];
      float A20 = cg[2], A21 = cg[5], A22 = cg[8];
      float b00 = A11 * A22 - A12 * A21;
      float b01 = A02 * A21 - A01 * A22;
      float b02 = A01 * A12 - A02 * A11;
      float b10 = A12 * A20 - A10 * A22;
      float b11 = A00 * A22 - A02 * A20;
      float b12 = A02 * A10 - A00 * A12;
      float b20 = A10 * A21 - A11 * A20;
      float b21 = A01 * A20 - A00 * A21;
      float b22 = A00 * A11 - A01 * A10;
      float det = A00 * b00 + A01 * b10 + A02 * b20;
      float inv = 1.0f / det;
      const int node = g * NG_ + n0 + tid;
      float p0 = pos[(size_t)node * 3 + 0];
      float p1 = pos[(size_t)node * 3 + 1];
      float p2 = pos[(size_t)node * 3 + 2];
      float f0 = (b00 * p0 + b01 * p1 + b02 * p2) * inv;
      float f1 = (b10 * p0 + b11 * p1 + b12 * p2) * inv;
      float f2 = (b20 * p0 + b21 * p1 + b22 * p2) * inv;
      f_sh[tid * 4 + 0] = f0 - floorf(f0);
      f_sh[tid * 4 + 1] = f1 - floorf(f1);
      f_sh[tid * 4 + 2] = f2 - floorf(f2);
    }
    if (tid < 128) {
      nv_sh[tid * 3 + 0] = nvec[((size_t)g * 128 + tid) * 3 + 0];
      nv_sh[tid * 3 + 1] = nvec[((size_t)g * 128 + tid) * 3 + 1];
      nv_sh[tid * 3 + 2] = nvec[((size_t)g * 128 + tid) * 3 + 2];
      w_sh[tid] = sqrtf(w[(size_t)g * 128 + tid]);
    }
    __syncthreads();
    const int n_l = tid >> 4, m0 = (tid & 15) * 8;
    float f0 = f_sh[n_l * 4 + 0], f1 = f_sh[n_l * 4 + 1], f2 = f_sh[n_l * 4 + 2];
    short8 pc, ps;
#pragma unroll
    for (int i = 0; i < 8; ++i) {
      int m = m0 + i;
      float dot = f0 * (float)nv_sh[m * 3] + f1 * (float)nv_sh[m * 3 + 1] +
                  f2 * (float)nv_sh[m * 3 + 2];
      float tr = dot - floorf(dot);
      float sn = __builtin_amdgcn_sinf(tr);
      float cs = __builtin_amdgcn_cosf(tr);
      float sq = w_sh[m];
      pc[i] = f2bf(sq * cs);
      ps[i] = f2bf(sq * sn);
    }
    const int node = g * NG_ + n0 + n_l;
    *(short8*)&CT[(size_t)node * 128 + m0] = pc;
    *(short8*)&ST[(size_t)node * 128 + m0] = ps;
  }
}

// ================= K_EV2: single-shot partial E*V over one 64-col chunk,
// gated + atomically accumulated into out (zeroed by k_prep). [round-7 proven]
__global__ __launch_bounds__(512) void k_EV2(
    const short* __restrict__ QA, const short* __restrict__ KA,
    const short* __restrict__ VT, const short* __restrict__ CT,
    const short* __restrict__ ST, const float* __restrict__ GF,
    float* __restrict__ out) {
  __shared__ short smem[47104];  // 92 KB
  short* tQ  = smem;             // 32x128
  short* tCr = smem + 4096;
  short* tSr = smem + 8192;
  short* tKA = smem + 12288;     // 64x128
  short* tCc = smem + 20480;
  short* tSc = smem + 28672;
  short* tV  = smem + 36864;     // 128(d) x 64(n')
  short* tE  = smem + 45056;     // 32x64
  const int tid = threadIdx.x;
  const int bid = blockIdx.x;
  const int g = bid >> 5;
  const int rt = (bid >> 2) & 7;
  const int cc = bid & 3;
  const int R0 = rt * 32, C0 = cc * 64;
  const int gn = g * NG_;
  const int wid = tid >> 6, lane = tid & 63;
  const int frow = lane & 15, kq = (lane >> 4) * 8;
  const int orow = (lane >> 4) * 4, ocol = lane & 15;
  const int rfrag = wid >> 2;          // 0..1
  const int cfrag = wid & 3;           // 0..3 (E col frag / PV d block)

  // row-side staging: 512 threads cover 32x16 short8
  {
    int row = tid >> 4, c8 = (tid & 15) * 8;
    int idx = (row * 128 + c8) ^ ((row & 7) << 3);
    size_t ga = (size_t)(gn + R0 + row) * 128 + c8;
    *(short8*)&tQ[idx] = *(const short8*)&QA[ga];
    *(short8*)&tCr[idx] = *(const short8*)&CT[ga];
    *(short8*)&tSr[idx] = *(const short8*)&ST[ga];
  }
  // col-side staging: KA/Cc/Sc (64x128) + V (128x64)
#pragma unroll
  for (int it = 0; it < 2; ++it) {
    int e = tid + it * 512;
    int row = e >> 4, c8 = (e & 15) * 8;
    int idx = (row * 128 + c8) ^ ((row & 7) << 3);
    size_t ga = (size_t)(gn + C0 + row) * 128 + c8;
    *(short8*)&tKA[idx] = *(const short8*)&KA[ga];
    *(short8*)&tCc[idx] = *(const short8*)&CT[ga];
    *(short8*)&tSc[idx] = *(const short8*)&ST[ga];
    int d = e >> 3, n8 = (e & 7) * 8;
    *(short8*)&tV[(d * 64 + n8) ^ ((d & 7) << 3)] =
        *(const short8*)&VT[((size_t)g * 128 + d) * 256 + C0 + n8];
  }
  __syncthreads();
  // ---- E fragment: each wave one 16x16 frag at (rfrag, cfrag)
  f32x4 gc = {}, gs = {}, qc = {}, qs = {};
#pragma unroll
  for (int ks = 0; ks < 4; ++ks) {
    int kk = ks * 32 + kq, kk2 = (kk + 64) & 127;
    short8 aq = ldf(tQ, rfrag * 16 + frow, kk);
    short8 ka = ldf(tKA, cfrag * 16 + frow, kk);
    short8 t = ldf(tKA, cfrag * 16 + frow, kk2);
    short8 kb = (ks >= 2) ? neg8(t) : t;
    gc = MFMA16(aq, ka, gc);
    gs = MFMA16(aq, kb, gs);
  }
#pragma unroll
  for (int ks = 0; ks < 8; ++ks) {
    const bool lo = ks < 4;
    int kk = (ks & 3) * 32 + kq;
    short8 cr = ldf(tCr, rfrag * 16 + frow, kk);
    short8 sr = ldf(tSr, rfrag * 16 + frow, kk);
    short8 xr = lo ? cr : sr;
    short8 yr = lo ? sr : neg8(cr);
    short8 xc = ldf(lo ? tCc : tSc, cfrag * 16 + frow, kk);
    qc = MFMA16(xr, xc, qc);
    qs = MFMA16(yr, xc, qs);
  }
  // combine -> bounce E frag through LDS (bf16)
  {
    int col = cfrag * 16 + ocol;
#pragma unroll
    for (int r = 0; r < 4; ++r) {
      int row = rfrag * 16 + orow + r;
      float ev = gc[r] * qc[r] + gs[r] * qs[r];
      tE[(row * 64 + col) ^ ((row & 7) << 3)] = f2bf(ev);
    }
  }
  __syncthreads();
  // ---- PV partial: wave (rfrag, cfrag) -> rows rfrag*16, d cols cfrag*32..+31
  f32x4 oacc[2] = {};
#pragma unroll
  for (int ks = 0; ks < 2; ++ks) {
    int kk = ks * 32 + kq;
    short8 a = ldf64(tE, rfrag * 16 + frow, kk);
#pragma unroll
    for (int j = 0; j < 2; ++j) {
      short8 b = ldf64(tV, cfrag * 32 + j * 16 + frow, kk);
      oacc[j] = MFMA16(a, b, oacc[j]);
    }
  }
  // gated atomic accumulate (gate is row-constant, distributes over the sum)
#pragma unroll
  for (int r = 0; r < 4; ++r) {
    int node = gn + R0 + rfrag * 16 + orow + r;
    float fct = GF[node] * SCALE_E;
#pragma unroll
    for (int j = 0; j < 2; ++j)
      unsafeAtomicAdd(&out[(size_t)node * H_ + cfrag * 32 + j * 16 + ocol],
                      oacc[j][r] * fct);
  }
}

extern "C" void kernel_launch(void* const* d_in, const int* in_sizes, int n_in,
                              void* d_out, int out_size, void* d_ws,
                              size_t ws_size, hipStream_t stream) {
  const float* node_feat = (const float*)d_in[0];
  const float* positions = (const float*)d_in[1];
  const float* cell = (const float*)d_in[2];
  const float* w = (const float*)d_in[3];
  const float* Wqkv = (const float*)d_in[4];
  const float* Wvg = (const float*)d_in[5];
  const float* bvg = (const float*)d_in[6];
  const float* Whg = (const float*)d_in[7];
  const float* bhg = (const float*)d_in[8];
  const float* Wmg = (const float*)d_in[9];
  const float* bmg = (const float*)d_in[10];
  const int* nvec = (const int*)d_in[11];
  float* out = (float*)d_out;
  char* ws = (char*)d_ws;

  short* QA = (short*)(ws + OFF_QA);
  short* KA = (short*)(ws + OFF_KA);
  short* VT = (short*)(ws + OFF_VT);
  short* CT = (short*)(ws + OFF_CT);
  short* ST = (short*)(ws + OFF_ST);
  float* GF = (float*)(ws + OFF_GF);
  float* out_gate = out + (size_t)NTOT_ * H_;

  k_prep<<<192, 512, 0, stream>>>(node_feat, Wqkv, Wvg, bvg, Whg, bhg, Wmg, bmg,
                                  cell, positions, nvec, w, QA, KA, VT, CT, ST,
                                  GF, out_gate, out);
  k_EV2<<<256, 512, 0, stream>>>(QA, KA, VT, CT, ST, GF, out);
}